// Round 2
// baseline (1166.936 us; speedup 1.0000x reference)
//
#include <hip/hip_runtime.h>

// Problem constants (from reference setup_inputs)
#define N_NODES 200000
#define N_EDGES 6400000
#define NGRAPH  128
#define H       32
#define NB_SCAN ((N_NODES + 255) / 256)   // 782 blocks for the node-count scan

// ---------------------------------------------------------------------------
// K0: h_global_graph = relu(x_global @ W_global + b_global)   [128, 32]
// ---------------------------------------------------------------------------
__global__ void k_global_enc(const float* __restrict__ xg,
                             const float* __restrict__ Wg,
                             const float* __restrict__ bg,
                             float* __restrict__ hg) {
    int tid = blockIdx.x * blockDim.x + threadIdx.x;
    if (tid >= NGRAPH * H) return;
    int b = tid >> 5, t = tid & 31;
    float acc = bg[t];
#pragma unroll
    for (int k = 0; k < 8; ++k)
        acc = fmaf(xg[b * 8 + k], Wg[k * H + t], acc);
    hg[tid] = fmaxf(acc, 0.f);
}

// ---------------------------------------------------------------------------
// K1: per-node encoder. 32 threads per node (8 nodes / 256-thread block).
// m[n] = relu(h0 @ W_msg + b_msg)   (per-source message == self-loop msg)
// s[n] = h0 @ W_self + b_self       (pre-relu self path)
// ---------------------------------------------------------------------------
__global__ void k_node_enc(const float* __restrict__ xl,
                           const int*   __restrict__ batch,
                           const float* __restrict__ hg,
                           const float* __restrict__ Wl,   const float* __restrict__ bl,
                           const float* __restrict__ Wmix, const float* __restrict__ bmix,
                           const float* __restrict__ Wmsg, const float* __restrict__ bmsg,
                           const float* __restrict__ Wself,const float* __restrict__ bself,
                           float* __restrict__ m, float* __restrict__ s) {
    __shared__ float hcat[8][96];
    __shared__ float h0s[8][32];

    int tid   = threadIdx.x;
    int local = tid >> 5;
    int t     = tid & 31;
    int n     = blockIdx.x * 8 + local;   // 25000 blocks * 8 == 200000 exactly

    float hl = bl[t];
#pragma unroll
    for (int k = 0; k < 16; ++k)
        hl = fmaf(xl[n * 16 + k], Wl[k * H + t], hl);
    hl = fmaxf(hl, 0.f);

    float hgv = hg[batch[n] * H + t];

    hcat[local][t]      = hl;
    hcat[local][32 + t] = hgv;
    hcat[local][64 + t] = hl * hgv;
    __syncthreads();

    float h0 = bmix[t];
#pragma unroll
    for (int k = 0; k < 96; ++k)
        h0 = fmaf(hcat[local][k], Wmix[k * H + t], h0);
    h0 = fmaxf(h0, 0.f);
    h0s[local][t] = h0;
    __syncthreads();

    float mv = bmsg[t], sv = bself[t];
#pragma unroll
    for (int k = 0; k < 32; ++k) {
        float hv = h0s[local][k];
        mv = fmaf(hv, Wmsg[k * H + t], mv);
        sv = fmaf(hv, Wself[k * H + t], sv);
    }
    m[n * H + t] = fmaxf(mv, 0.f);
    s[n * H + t] = sv;
}

// ---------------------------------------------------------------------------
// CSR build phase: count -> scan -> scatter.  2 atomics/edge instead of 32.
// ---------------------------------------------------------------------------
__global__ void k_count(const int* __restrict__ ei, int* __restrict__ cnt) {
    int e = blockIdx.x * 256 + threadIdx.x;
    if (e >= N_EDGES) return;
    atomicAdd(&cnt[ei[N_EDGES + e]], 1);
}

__global__ void k_blocksum(const int* __restrict__ cnt, int* __restrict__ bsum) {
    int b = blockIdx.x, t = threadIdx.x, n = b * 256 + t;
    int v = (n < N_NODES) ? cnt[n] : 0;
#pragma unroll
    for (int off = 32; off >= 1; off >>= 1)
        v += __shfl_down(v, off, 64);
    __shared__ int w4[4];
    if ((t & 63) == 0) w4[t >> 6] = v;
    __syncthreads();
    if (t == 0) bsum[b] = w4[0] + w4[1] + w4[2] + w4[3];
}

// single block of 1024: Hillis-Steele inclusive scan of the 782 block sums
__global__ void k_scan_bsums(const int* __restrict__ bsum, int* __restrict__ boff) {
    __shared__ int sd[1024];
    int t = threadIdx.x;
    sd[t] = (t < NB_SCAN) ? bsum[t] : 0;
    __syncthreads();
#pragma unroll
    for (int off = 1; off < 1024; off <<= 1) {
        int v = (t >= off) ? sd[t - off] : 0;
        __syncthreads();
        sd[t] += v;
        __syncthreads();
    }
    if (t < NB_SCAN) boff[t] = (t == 0) ? 0 : sd[t - 1];
}

// in-place: cnt[n] -> exclusive row start (cursor)
__global__ void k_make_cursor(int* __restrict__ cnt, const int* __restrict__ boff) {
    __shared__ int sd[256];
    int b = blockIdx.x, t = threadIdx.x, n = b * 256 + t;
    int c = (n < N_NODES) ? cnt[n] : 0;
    sd[t] = c;
    __syncthreads();
#pragma unroll
    for (int off = 1; off < 256; off <<= 1) {
        int v = (t >= off) ? sd[t - off] : 0;
        __syncthreads();
        sd[t] += v;
        __syncthreads();
    }
    if (n < N_NODES) cnt[n] = boff[b] + sd[t] - c;   // exclusive start
}

// after this kernel, cursor[n] == row_end(n); row_start(n) == cursor[n-1]
__global__ void k_scatter(const int* __restrict__ ei,
                          int* __restrict__ cursor, int* __restrict__ csr) {
    int e = blockIdx.x * 256 + threadIdx.x;
    if (e >= N_EDGES) return;
    int src = ei[e];
    int dst = ei[N_EDGES + e];
    int pos = atomicAdd(&cursor[dst], 1);
    csr[pos] = src;
}

// ---------------------------------------------------------------------------
// K-aggr+final: 32 lanes per node walk the in-edge list (no atomics),
// then h = relu(aggr + m[n] + s[n]) and the 2-class head.
// ---------------------------------------------------------------------------
__global__ void k_aggr_final(const int* __restrict__ cursor,   // row ends
                             const int* __restrict__ csr,
                             const float* __restrict__ m,
                             const float* __restrict__ s,
                             const float* __restrict__ Wout,
                             const float* __restrict__ bout,
                             float* __restrict__ out) {
    int tid   = threadIdx.x;
    int local = tid >> 5;
    int t     = tid & 31;
    int n     = blockIdx.x * 8 + local;

    int start = (n == 0) ? 0 : cursor[n - 1];
    int end   = cursor[n];

    float a0 = 0.f, a1 = 0.f, a2 = 0.f, a3 = 0.f;
    int j = start;
    for (; j + 4 <= end; j += 4) {
        int s0 = csr[j], s1 = csr[j + 1], s2 = csr[j + 2], s3 = csr[j + 3];
        a0 += m[s0 * H + t];
        a1 += m[s1 * H + t];
        a2 += m[s2 * H + t];
        a3 += m[s3 * H + t];
    }
    for (; j < end; ++j) a0 += m[csr[j] * H + t];
    float acc = (a0 + a1) + (a2 + a3);

    int i = n * H + t;
    float h = fmaxf(acc + m[i] + s[i], 0.f);   // m[i] = self-loop message

    float p0 = h * Wout[t * 2 + 0];
    float p1 = h * Wout[t * 2 + 1];
#pragma unroll
    for (int off = 16; off >= 1; off >>= 1) {
        p0 += __shfl_down(p0, off, 32);
        p1 += __shfl_down(p1, off, 32);
    }
    if (t == 0) {
        out[n * 2 + 0] = p0 + bout[0];
        out[n * 2 + 1] = p1 + bout[1];
    }
}

// ---------------------------------------------------------------------------
extern "C" void kernel_launch(void* const* d_in, const int* in_sizes, int n_in,
                              void* d_out, int out_size, void* d_ws, size_t ws_size,
                              hipStream_t stream) {
    const float* xl    = (const float*)d_in[0];
    const float* xg    = (const float*)d_in[1];
    const int*   batch = (const int*)  d_in[2];
    const int*   ei    = (const int*)  d_in[3];
    const float* Wl    = (const float*)d_in[4];
    const float* bl    = (const float*)d_in[5];
    const float* Wg    = (const float*)d_in[6];
    const float* bg    = (const float*)d_in[7];
    const float* Wmix  = (const float*)d_in[8];
    const float* bmix  = (const float*)d_in[9];
    const float* Wmsg  = (const float*)d_in[10];
    const float* bmsg  = (const float*)d_in[11];
    const float* Wself = (const float*)d_in[12];
    const float* bself = (const float*)d_in[13];
    const float* Wout  = (const float*)d_in[14];
    const float* bout  = (const float*)d_in[15];
    float* out = (float*)d_out;

    // Workspace layout:
    //   hg   [128*32] f32
    //   m    [N*32]   f32
    //   s    [N*32]   f32
    //   cnt  [N]      i32   (becomes cursor, then row-ends)
    //   bsum [782]    i32
    //   boff [782]    i32
    //   csr  [E]      i32
    float* hg   = (float*)d_ws;
    float* m    = hg + NGRAPH * H;
    float* s    = m + (size_t)N_NODES * H;
    int*   cnt  = (int*)(s + (size_t)N_NODES * H);
    int*   bsum = cnt + N_NODES;
    int*   boff = bsum + NB_SCAN;
    int*   csr  = boff + NB_SCAN;

    hipMemsetAsync(cnt, 0, N_NODES * sizeof(int), stream);

    k_global_enc<<<(NGRAPH * H + 255) / 256, 256, 0, stream>>>(xg, Wg, bg, hg);

    k_count<<<N_EDGES / 256, 256, 0, stream>>>(ei, cnt);

    k_node_enc<<<N_NODES / 8, 256, 0, stream>>>(xl, batch, hg,
                                                Wl, bl, Wmix, bmix,
                                                Wmsg, bmsg, Wself, bself,
                                                m, s);

    k_blocksum<<<NB_SCAN, 256, 0, stream>>>(cnt, bsum);
    k_scan_bsums<<<1, 1024, 0, stream>>>(bsum, boff);
    k_make_cursor<<<NB_SCAN, 256, 0, stream>>>(cnt, boff);

    k_scatter<<<N_EDGES / 256, 256, 0, stream>>>(ei, cnt, csr);

    k_aggr_final<<<N_NODES / 8, 256, 0, stream>>>(cnt, csr, m, s, Wout, bout, out);
}